// Round 1
// baseline (510.746 us; speedup 1.0000x reference)
//
#include <hip/hip_runtime.h>
#include <hip/hip_bf16.h>

#define BATCH 32
#define LANCH 8400
#define NCLS 80
#define NGT 64
#define TOPK 13

// ---------------- Kernel 1: per (b, gt) row — iou, metric, top-13 ----------------
__global__ __launch_bounds__(256) void k_pergt(
    const float* __restrict__ pred_scores,   // (B, L, C)
    const float* __restrict__ pred_bboxes,   // (B, L, 4)
    const float* __restrict__ centers,       // (L, 2)
    const int*   __restrict__ gt_labels,     // (B, n)
    const float* __restrict__ gt_bboxes,     // (B, n, 4)
    const float* __restrict__ pad_mask,      // (B, n)
    float*       __restrict__ ws_iou,        // (B, n, L) masked ious
    unsigned char* __restrict__ ws_mask,     // (B, n, L) stage-1 positive mask
    float*       __restrict__ ws_mm,         // (B*n) per-gt max metric (zeroed here)
    float*       __restrict__ ws_mi)         // (B*n) per-gt max iou   (zeroed here)
{
    __shared__ float         s_met[LANCH];
    __shared__ unsigned char s_ing[LANCH];
    __shared__ float         s_rv[256];
    __shared__ int           s_ri[256];
    __shared__ int           s_top[TOPK];

    const int bg  = blockIdx.x;
    const int b   = bg >> 6;
    const int tid = threadIdx.x;
    if (tid == 0) { ws_mm[bg] = 0.f; ws_mi[bg] = 0.f; }

    const float4 gt  = reinterpret_cast<const float4*>(gt_bboxes)[bg];
    const float  pad = pad_mask[bg];
    const int    lab = gt_labels[bg];

    const float gw  = gt.z - gt.x, gh = gt.w - gt.y;
    const float ga  = gw * gh;
    const float gcx = (gt.x + gt.z) * 0.5f, gcy = (gt.y + gt.w) * 0.5f;
    const float atg = atanf(gw / gh);

    const float4* pb4 = reinterpret_cast<const float4*>(pred_bboxes) + (size_t)b * LANCH;
    const float2* cc2 = reinterpret_cast<const float2*>(centers);
    float* iou_row        = ws_iou + (size_t)bg * LANCH;
    const float* sc_row   = pred_scores + (size_t)b * LANCH * NCLS;

    for (int l = tid; l < LANCH; l += 256) {
        const float4 pb = pb4[l];
        const float2 cc = cc2[l];
        // is_in_gts
        float ltrb = fminf(fminf(cc.x - gt.x, cc.y - gt.y),
                           fminf(gt.z - cc.x, gt.w - cc.y));
        float ing  = (ltrb > 1e-9f) ? 1.f : 0.f;
        // CIoU
        float pw = pb.z - pb.x, ph = pb.w - pb.y;
        float pa = pw * ph;
        float iw = fmaxf(fminf(gt.z, pb.z) - fmaxf(gt.x, pb.x), 0.f);
        float ih = fmaxf(fminf(gt.w, pb.w) - fmaxf(gt.y, pb.y), 0.f);
        float inter = iw * ih;
        float uni   = ga + pa - inter;
        float iou   = inter / uni;
        float wi = fmaxf(fmaxf(gt.z, pb.z) - fminf(gt.x, pb.x), 0.f);
        float hi = fmaxf(fmaxf(gt.w, pb.w) - fminf(gt.y, pb.y), 0.f);
        float diag2 = wi * wi + hi * hi + 1e-7f;
        float pcx = (pb.x + pb.z) * 0.5f, pcy = (pb.y + pb.w) * 0.5f;
        float dx = gcx - pcx, dy = gcy - pcy;
        float diou = iou - (dx * dx + dy * dy) / diag2;
        float dat  = atg - atanf(pw / ph);
        float v    = 0.40528473456935109f * dat * dat;   // 4/pi^2
        float alpha = v / (1.f - iou + v + 1e-7f);
        float ciou  = diou - alpha * v;
        // nan_to_num + clip(>=0): fmaxf returns the non-NaN operand
        float ioum = fmaxf(ciou, 0.f) * ing * pad;
        iou_row[l] = ioum;
        float sc = sc_row[(size_t)l * NCLS + lab];
        float t2 = ioum * ioum;
        s_met[l] = sc * (t2 * t2 * t2);                  // score^1 * iou^6
        s_ing[l] = (unsigned char)ing;
    }
    __syncthreads();

    if (pad > 0.f) {
        // 13 rounds of block argmax (ties -> lowest index, matching jax.lax.top_k)
        for (int it = 0; it < TOPK; ++it) {
            float bv = -1.f; int bi = 0x7fffffff;
            for (int l = tid; l < LANCH; l += 256) {
                float v = s_met[l];
                if (v > bv) { bv = v; bi = l; }   // ascending scan: '>' keeps lowest idx
            }
            s_rv[tid] = bv; s_ri[tid] = bi;
            __syncthreads();
            for (int s = 128; s > 0; s >>= 1) {
                if (tid < s) {
                    float ov = s_rv[tid + s]; int oi = s_ri[tid + s];
                    float mv = s_rv[tid];     int mi = s_ri[tid];
                    if (ov > mv || (ov == mv && oi < mi)) { s_rv[tid] = ov; s_ri[tid] = oi; }
                }
                __syncthreads();
            }
            if (tid == 0) { int w = s_ri[0]; s_top[it] = w; s_met[w] = -2.f; }
            __syncthreads();
        }
        for (int l = tid; l < LANCH; l += 256) {
            unsigned char v = 0;
            #pragma unroll
            for (int k = 0; k < TOPK; ++k) if (s_top[k] == l) v = s_ing[l];
            ws_mask[(size_t)bg * LANCH + l] = v;
        }
    } else {
        for (int l = tid; l < LANCH; l += 256)
            ws_mask[(size_t)bg * LANCH + l] = 0;
    }
}

// ------------- Kernel 2: per anchor — conflict resolution, assignment -------------
__global__ __launch_bounds__(256) void k_anchor(
    const int*   __restrict__ gt_labels,
    const float* __restrict__ gt_bboxes,
    const float* __restrict__ pred_scores,
    const float* __restrict__ ws_iou,
    unsigned char* __restrict__ ws_mask,     // in: stage1, out: final mask
    float*       __restrict__ ws_mm,
    float*       __restrict__ ws_mi,
    float*       __restrict__ out_labels,
    float*       __restrict__ out_bboxes,
    float*       __restrict__ out_fg)
{
    const int idx = blockIdx.x * 256 + threadIdx.x;
    if (idx >= BATCH * LANCH) return;
    const int b = idx / LANCH;
    const int l = idx - b * LANCH;
    const float* iou_col       = ws_iou  + (size_t)b * NGT * LANCH + l;
    unsigned char* m_col       = ws_mask + (size_t)b * NGT * LANCH + l;

    int   sum1   = 0;
    float maxiou = 0.f;
    for (int g = 0; g < NGT; ++g) {
        float v = iou_col[(size_t)g * LANCH];
        sum1   += m_col[(size_t)g * LANCH];
        maxiou  = fmaxf(maxiou, v);
    }
    int sumf = 0, first = -1;
    for (int g = 0; g < NGT; ++g) {
        float v = iou_col[(size_t)g * LANCH];
        unsigned char mf;
        if (sum1 > 1) mf = (v == maxiou) ? 1 : 0;       // is_max_iou replacement
        else          mf = m_col[(size_t)g * LANCH];
        m_col[(size_t)g * LANCH] = mf;
        if (mf) {
            sumf++;
            if (first < 0) first = g;
            float sc = pred_scores[((size_t)b * LANCH + l) * NCLS + gt_labels[b * NGT + g]];
            float t2 = v * v;
            float met = sc * (t2 * t2 * t2);
            atomicMax(reinterpret_cast<int*>(ws_mm + b * NGT + g), __float_as_int(met));
            atomicMax(reinterpret_cast<int*>(ws_mi + b * NGT + g), __float_as_int(v));
        }
    }
    const int assigned = (first < 0) ? 0 : first;
    out_labels[idx] = (sumf > 0) ? (float)gt_labels[b * NGT + assigned] : 80.f;
    reinterpret_cast<float4*>(out_bboxes)[idx] =
        reinterpret_cast<const float4*>(gt_bboxes)[b * NGT + assigned];
    out_fg[idx] = (sumf > 0) ? 1.f : 0.f;
}

// ---------------- Kernel 3: per anchor — norm + one-hot score write ----------------
__global__ __launch_bounds__(256) void k_scores(
    const unsigned char* __restrict__ ws_mask,
    const float* __restrict__ ws_iou,
    const float* __restrict__ pred_scores,
    const int*   __restrict__ gt_labels,
    const float* __restrict__ ws_mm,
    const float* __restrict__ ws_mi,
    const float* __restrict__ out_labels,
    float*       __restrict__ out_scores)
{
    const int idx = blockIdx.x * 256 + threadIdx.x;
    if (idx >= BATCH * LANCH) return;
    const int b = idx / LANCH;
    const int l = idx - b * LANCH;
    const unsigned char* m_col = ws_mask + (size_t)b * NGT * LANCH + l;
    const float* iou_col       = ws_iou  + (size_t)b * NGT * LANCH + l;

    float norm = 0.f;
    for (int g = 0; g < NGT; ++g) {
        if (m_col[(size_t)g * LANCH]) {
            float v  = iou_col[(size_t)g * LANCH];
            float sc = pred_scores[((size_t)b * LANCH + l) * NCLS + gt_labels[b * NGT + g]];
            float t2 = v * v;
            float met = sc * (t2 * t2 * t2);
            float am = met / (ws_mm[b * NGT + g] + 1e-9f) * ws_mi[b * NGT + g];
            norm = fmaxf(norm, am);
        }
    }
    const int lab = (int)out_labels[idx];
    float* row = out_scores + (size_t)idx * NCLS;
    for (int c = 0; c < NCLS; c += 4) {
        float4 w = make_float4(0.f, 0.f, 0.f, 0.f);
        if (lab >= c && lab < c + 4) (&w.x)[lab - c] = norm;
        *reinterpret_cast<float4*>(row + c) = w;
    }
}

extern "C" void kernel_launch(void* const* d_in, const int* in_sizes, int n_in,
                              void* d_out, int out_size, void* d_ws, size_t ws_size,
                              hipStream_t stream) {
    const float* pred_scores = (const float*)d_in[0];   // (32, 8400, 80)
    const float* pred_bboxes = (const float*)d_in[1];   // (32, 8400, 4)
    const float* centers     = (const float*)d_in[2];   // (8400, 2)
    const int*   gt_labels   = (const int*)  d_in[3];   // (32, 64, 1)
    const float* gt_bboxes   = (const float*)d_in[4];   // (32, 64, 4)
    const float* pad_mask    = (const float*)d_in[5];   // (32, 64, 1)

    const size_t BNL = (size_t)BATCH * NGT * LANCH;     // 17,203,200
    char* ws = (char*)d_ws;
    float*         ws_iou  = (float*)ws;                       // BNL f32 = 68.8 MB
    unsigned char* ws_mask = (unsigned char*)(ws + BNL * 4);   // BNL u8  = 17.2 MB
    float*         ws_mm   = (float*)(ws + BNL * 5);           // 2048 f32
    float*         ws_mi   = ws_mm + BATCH * NGT;              // 2048 f32

    float* out        = (float*)d_out;
    float* out_labels = out;                                   // (B, L)
    float* out_bboxes = out + (size_t)BATCH * LANCH;           // (B, L, 4)
    float* out_scores = out + (size_t)BATCH * LANCH * 5;       // (B, L, 80)
    float* out_fg     = out + (size_t)BATCH * LANCH * 5 + (size_t)BATCH * LANCH * NCLS;

    k_pergt<<<BATCH * NGT, 256, 0, stream>>>(
        pred_scores, pred_bboxes, centers, gt_labels, gt_bboxes, pad_mask,
        ws_iou, ws_mask, ws_mm, ws_mi);

    const int na = BATCH * LANCH;                               // 268,800
    k_anchor<<<(na + 255) / 256, 256, 0, stream>>>(
        gt_labels, gt_bboxes, pred_scores, ws_iou, ws_mask, ws_mm, ws_mi,
        out_labels, out_bboxes, out_fg);

    k_scores<<<(na + 255) / 256, 256, 0, stream>>>(
        ws_mask, ws_iou, pred_scores, gt_labels, ws_mm, ws_mi,
        out_labels, out_scores);
}

// Round 2
// 285.119 us; speedup vs baseline: 1.7913x; 1.7913x over previous
//
#include <hip/hip_runtime.h>

#define BATCH 32
#define LANCH 8400
#define NCLS  80
#define NGT   64
#define TOPK  13
#define NCHUNK 33          // ceil(8400/256)
#define NQ4   2100         // 8400/4

// ---- shared per-block GT data ----
struct GtLds {
  float4 box[NGT];
  float  ga[NGT], gcx[NGT], gcy[NGT], atg[NGT], padf[NGT];
  int    lab[NGT];
};

__device__ __forceinline__ void load_gt(GtLds& s, int b,
    const float* gt_bboxes, const int* gt_labels, const float* pad_mask, int t)
{
  if (t < NGT) {
    float4 g = reinterpret_cast<const float4*>(gt_bboxes)[b * NGT + t];
    s.box[t] = g;
    float gw = g.z - g.x, gh = g.w - g.y;
    s.ga[t]  = gw * gh;
    s.gcx[t] = (g.x + g.z) * 0.5f;
    s.gcy[t] = (g.y + g.w) * 0.5f;
    s.atg[t] = atanf(gw / gh);
    s.padf[t] = pad_mask[b * NGT + t];
    s.lab[t]  = gt_labels[b * NGT + t];
  }
}

// clipped CIoU (no ing/pad factors) — shared by all kernels so recompute matches
__device__ __forceinline__ float ciou_core(
    float4 pb, float pa, float pcx, float pcy, float atp,
    float4 gb, float ga, float gcx, float gcy, float atg)
{
  float iw = fmaxf(fminf(gb.z, pb.z) - fmaxf(gb.x, pb.x), 0.f);
  float ih = fmaxf(fminf(gb.w, pb.w) - fmaxf(gb.y, pb.y), 0.f);
  float inter = iw * ih;
  float uni   = ga + pa - inter;
  float iou   = inter / uni;
  float wi = fmaxf(fmaxf(gb.z, pb.z) - fminf(gb.x, pb.x), 0.f);
  float hi = fmaxf(fmaxf(gb.w, pb.w) - fminf(gb.y, pb.y), 0.f);
  float diag2 = wi * wi + hi * hi + 1e-7f;
  float dx = gcx - pcx, dy = gcy - pcy;
  float diou = iou - (dx * dx + dy * dy) / diag2;
  float dat = atg - atp;
  float v = 0.40528473456935109f * dat * dat;     // 4/pi^2
  float alpha = v / (1.f - iou + v + 1e-7f);
  return fmaxf(diou - alpha * v, 0.f);            // nan_to_num + clip>=0
}

// masked iou = clip(ciou) * is_in_gts * pad  (early-out exact 0)
__device__ __forceinline__ float masked_ciou(
    float4 pb, float pa, float pcx, float pcy, float atp, float2 cc,
    float4 gb, float ga, float gcx, float gcy, float atg, float padf)
{
  float ltrb = fminf(fminf(cc.x - gb.x, cc.y - gb.y),
                     fminf(gb.z - cc.x, gb.w - cc.y));
  if (!(ltrb > 1e-9f) || padf == 0.f) return 0.f;
  return ciou_core(pb, pa, pcx, pcy, atp, gb, ga, gcx, gcy, atg);
}

// ---------------- K1a: metrics + is_in_gts mask ----------------
__global__ __launch_bounds__(256) void k_pairs(
    const float* __restrict__ pred_scores,
    const float* __restrict__ pred_bboxes,
    const float* __restrict__ centers,
    const int*   __restrict__ gt_labels,
    const float* __restrict__ gt_bboxes,
    const float* __restrict__ pad_mask,
    float*       __restrict__ ws_met,
    unsigned char* __restrict__ ws_mask,
    float*       __restrict__ ws_mm,
    float*       __restrict__ ws_mi)
{
  __shared__ GtLds s;
  const int b = blockIdx.y, t = threadIdx.x;
  load_gt(s, b, gt_bboxes, gt_labels, pad_mask, t);
  if (blockIdx.x == 0) {                 // zero per-gt maxima once per batch
    if (t < NGT)            ws_mm[b * NGT + t] = 0.f;
    else if (t < 2 * NGT)   ws_mi[b * NGT + t - NGT] = 0.f;
  }
  __syncthreads();
  const int l = blockIdx.x * 256 + t;
  if (l >= LANCH) return;

  const float4 pb = reinterpret_cast<const float4*>(pred_bboxes)[(size_t)b * LANCH + l];
  const float2 cc = reinterpret_cast<const float2*>(centers)[l];
  const float pw = pb.z - pb.x, ph = pb.w - pb.y;
  const float pa = pw * ph;
  const float pcx = (pb.x + pb.z) * 0.5f, pcy = (pb.y + pb.w) * 0.5f;
  const float atp = atanf(pw / ph);
  const float* srow = pred_scores + ((size_t)b * LANCH + l) * NCLS;

  size_t idx = (size_t)(b * NGT) * LANCH + l;
  for (int g = 0; g < NGT; ++g, idx += LANCH) {
    if (s.padf[g] == 0.f) { ws_mask[idx] = 0; continue; }
    const float4 gb = s.box[g];
    float ltrb = fminf(fminf(cc.x - gb.x, cc.y - gb.y),
                       fminf(gb.z - cc.x, gb.w - cc.y));
    unsigned char ing = (ltrb > 1e-9f) ? 1 : 0;
    ws_mask[idx] = ing;
    float met = 0.f;
    if (ing) {
      float io = ciou_core(pb, pa, pcx, pcy, atp,
                           gb, s.ga[g], s.gcx[g], s.gcy[g], s.atg[g]);
      float t2 = io * io;
      met = srow[s.lab[g]] * (t2 * t2 * t2);   // score^1 * iou^6
    }
    ws_met[idx] = met;
  }
}

// ---------------- K1b: exact top-13 per (b,gt) row ----------------
__device__ __forceinline__ unsigned long long umax64(unsigned long long a,
                                                     unsigned long long b)
{ return a > b ? a : b; }

__device__ __forceinline__ unsigned long long mkkey(unsigned int bits, int l)
{ return ((unsigned long long)bits << 32) | (unsigned int)(0x7FFFFFFF - l); }

__global__ __launch_bounds__(256) void k_topk(
    const float* __restrict__ ws_met,
    unsigned char* __restrict__ ws_mask,
    const float* __restrict__ pad_mask)
{
  const int bg = blockIdx.x;
  if (pad_mask[bg] == 0.f) return;      // row already all-zero mask from k_pairs
  __shared__ uint4 s_bits4[NQ4];
  __shared__ unsigned long long s_seg[256];
  __shared__ int s_top[TOPK];
  __shared__ unsigned char s_ingv[TOPK];
  unsigned int* s_bits = reinterpret_cast<unsigned int*>(s_bits4);
  const int t = threadIdx.x;
  const uint4* mrow = reinterpret_cast<const uint4*>(ws_met + (size_t)bg * LANCH);

  unsigned long long best = 0;
  for (int j = t; j < NQ4; j += 256) {
    uint4 u = mrow[j];
    s_bits4[j] = u;
    int l0 = j * 4;
    best = umax64(best, mkkey(u.x, l0));
    best = umax64(best, mkkey(u.y, l0 + 1));
    best = umax64(best, mkkey(u.z, l0 + 2));
    best = umax64(best, mkkey(u.w, l0 + 3));
  }
  s_seg[t] = best;
  __syncthreads();

  for (int it = 0; it < TOPK; ++it) {
    if (t < 64) {
      unsigned long long k = s_seg[t];
      k = umax64(k, s_seg[t + 64]);
      k = umax64(k, s_seg[t + 128]);
      k = umax64(k, s_seg[t + 192]);
      #pragma unroll
      for (int off = 32; off > 0; off >>= 1) {
        unsigned long long o =
          (((unsigned long long)(unsigned int)__shfl_down((unsigned int)(k >> 32), off)) << 32)
          | (unsigned int)__shfl_down((unsigned int)(k & 0xFFFFFFFFu), off);
        if (o > k) k = o;
      }
      if (t == 0) {
        int l = 0x7FFFFFFF - (int)(unsigned int)(k & 0xFFFFFFFFu);
        s_top[it] = l;
        s_bits[l] = 0xFFFFFFFFu;        // dead sentinel (> any finite metric bits)
      }
    }
    __syncthreads();
    const int lw = s_top[it];
    const int owner = (lw >> 2) & 255;  // chunk j = l/4, owner = j % 256
    if (t == owner) {
      unsigned long long nb = 0;
      for (int j = t; j < NQ4; j += 256) {
        uint4 u = s_bits4[j];
        int l0 = j * 4;
        if (u.x != 0xFFFFFFFFu) nb = umax64(nb, mkkey(u.x, l0));
        if (u.y != 0xFFFFFFFFu) nb = umax64(nb, mkkey(u.y, l0 + 1));
        if (u.z != 0xFFFFFFFFu) nb = umax64(nb, mkkey(u.z, l0 + 2));
        if (u.w != 0xFFFFFFFFu) nb = umax64(nb, mkkey(u.w, l0 + 3));
      }
      s_seg[t] = nb;
    }
    __syncthreads();
  }

  unsigned char* mrow8 = ws_mask + (size_t)bg * LANCH;
  if (t < TOPK) s_ingv[t] = mrow8[s_top[t]];   // is_in_gts at winners
  __syncthreads();
  for (int j = t; j < NQ4; j += 256)
    reinterpret_cast<unsigned int*>(mrow8)[j] = 0u;
  __syncthreads();
  if (t == 0) {
    #pragma unroll
    for (int k = 0; k < TOPK; ++k) mrow8[s_top[k]] = s_ingv[k];
  }
}

// ---------------- K2: per-anchor conflict resolution + assignment ----------------
__global__ __launch_bounds__(256) void k_assign(
    const float* __restrict__ pred_scores,
    const float* __restrict__ pred_bboxes,
    const float* __restrict__ centers,
    const int*   __restrict__ gt_labels,
    const float* __restrict__ gt_bboxes,
    const float* __restrict__ pad_mask,
    unsigned char* __restrict__ ws_mask,
    float*       __restrict__ ws_mm,
    float*       __restrict__ ws_mi,
    float*       __restrict__ out_labels,
    float*       __restrict__ out_bboxes,
    float*       __restrict__ out_fg)
{
  __shared__ GtLds s;
  const int b = blockIdx.y, t = threadIdx.x;
  load_gt(s, b, gt_bboxes, gt_labels, pad_mask, t);
  __syncthreads();
  const int l = blockIdx.x * 256 + t;
  if (l >= LANCH) return;
  const int idx = b * LANCH + l;

  unsigned char* mcol = ws_mask + (size_t)(b * NGT) * LANCH + l;
  unsigned long long mbits = 0;
  for (int g = 0; g < NGT; ++g)
    mbits |= (unsigned long long)(mcol[(size_t)g * LANCH] != 0) << g;
  const int sum1 = __popcll(mbits);

  if (sum1 == 0) {
    out_labels[idx] = (float)NCLS;      // background
    reinterpret_cast<float4*>(out_bboxes)[idx] = s.box[0];
    out_fg[idx] = 0.f;
    return;
  }

  const float4 pb = reinterpret_cast<const float4*>(pred_bboxes)[(size_t)b * LANCH + l];
  const float2 cc = reinterpret_cast<const float2*>(centers)[l];
  const float pw = pb.z - pb.x, ph = pb.w - pb.y;
  const float pa = pw * ph;
  const float pcx = (pb.x + pb.z) * 0.5f, pcy = (pb.y + pb.w) * 0.5f;
  const float atp = atanf(pw / ph);
  const float* srow = pred_scores + ((size_t)b * LANCH + l) * NCLS;

  unsigned long long fbits;
  if (sum1 > 1) {
    // max + tie-set from ONE evaluation per g (self-consistent equality)
    float mx = 0.f;
    unsigned long long eq = 0;
    for (int g = 0; g < NGT; ++g) {
      float io = masked_ciou(pb, pa, pcx, pcy, atp, cc, s.box[g],
                             s.ga[g], s.gcx[g], s.gcy[g], s.atg[g], s.padf[g]);
      if (io > mx)       { mx = io; eq = 1ull << g; }
      else if (io == mx) { eq |= 1ull << g; }
    }
    fbits = eq;
    for (int g = 0; g < NGT; ++g)
      mcol[(size_t)g * LANCH] = (unsigned char)((eq >> g) & 1ull);
  } else {
    fbits = mbits;
  }

  unsigned long long bits = fbits;
  while (bits) {
    int g = __ffsll((unsigned long long)bits) - 1;
    bits &= bits - 1;
    float io = masked_ciou(pb, pa, pcx, pcy, atp, cc, s.box[g],
                           s.ga[g], s.gcx[g], s.gcy[g], s.atg[g], s.padf[g]);
    float t2 = io * io;
    float met = srow[s.lab[g]] * (t2 * t2 * t2);
    atomicMax(reinterpret_cast<int*>(ws_mm + b * NGT + g), __float_as_int(met));
    atomicMax(reinterpret_cast<int*>(ws_mi + b * NGT + g), __float_as_int(io));
  }
  const int first = __ffsll((unsigned long long)fbits) - 1;
  out_labels[idx] = (float)s.lab[first];
  reinterpret_cast<float4*>(out_bboxes)[idx] = s.box[first];
  out_fg[idx] = 1.f;
}

// ---------------- K3: sparse normalized score writes ----------------
__global__ __launch_bounds__(256) void k_scores(
    const float* __restrict__ pred_scores,
    const float* __restrict__ pred_bboxes,
    const float* __restrict__ centers,
    const int*   __restrict__ gt_labels,
    const float* __restrict__ gt_bboxes,
    const float* __restrict__ pad_mask,
    const unsigned char* __restrict__ ws_mask,
    const float* __restrict__ ws_mm,
    const float* __restrict__ ws_mi,
    const float* __restrict__ out_labels,
    const float* __restrict__ out_fg,
    float*       __restrict__ out_scores)
{
  __shared__ GtLds s;
  __shared__ float smm[NGT], smi[NGT];
  const int b = blockIdx.y, t = threadIdx.x;
  load_gt(s, b, gt_bboxes, gt_labels, pad_mask, t);
  if (t < NGT) { smm[t] = ws_mm[b * NGT + t]; smi[t] = ws_mi[b * NGT + t]; }
  __syncthreads();
  const int l = blockIdx.x * 256 + t;
  if (l >= LANCH) return;
  const int idx = b * LANCH + l;
  if (out_fg[idx] == 0.f) return;       // ~90% exit; zeros come from memset

  const unsigned char* mcol = ws_mask + (size_t)(b * NGT) * LANCH + l;
  unsigned long long bits = 0;
  for (int g = 0; g < NGT; ++g)
    bits |= (unsigned long long)(mcol[(size_t)g * LANCH] != 0) << g;

  const float4 pb = reinterpret_cast<const float4*>(pred_bboxes)[(size_t)b * LANCH + l];
  const float2 cc = reinterpret_cast<const float2*>(centers)[l];
  const float pw = pb.z - pb.x, ph = pb.w - pb.y;
  const float pa = pw * ph;
  const float pcx = (pb.x + pb.z) * 0.5f, pcy = (pb.y + pb.w) * 0.5f;
  const float atp = atanf(pw / ph);
  const float* srow = pred_scores + ((size_t)b * LANCH + l) * NCLS;

  float norm = 0.f;
  while (bits) {
    int g = __ffsll((unsigned long long)bits) - 1;
    bits &= bits - 1;
    float io = masked_ciou(pb, pa, pcx, pcy, atp, cc, s.box[g],
                           s.ga[g], s.gcx[g], s.gcy[g], s.atg[g], s.padf[g]);
    float t2 = io * io;
    float met = srow[s.lab[g]] * (t2 * t2 * t2);
    norm = fmaxf(norm, met / (smm[g] + 1e-9f) * smi[g]);
  }
  out_scores[(size_t)idx * NCLS + (int)out_labels[idx]] = norm;
}

extern "C" void kernel_launch(void* const* d_in, const int* in_sizes, int n_in,
                              void* d_out, int out_size, void* d_ws, size_t ws_size,
                              hipStream_t stream) {
  const float* pred_scores = (const float*)d_in[0];
  const float* pred_bboxes = (const float*)d_in[1];
  const float* centers     = (const float*)d_in[2];
  const int*   gt_labels   = (const int*)  d_in[3];
  const float* gt_bboxes   = (const float*)d_in[4];
  const float* pad_mask    = (const float*)d_in[5];

  const size_t BNL = (size_t)BATCH * NGT * LANCH;       // 17,203,200
  char* ws = (char*)d_ws;
  float*         ws_met  = (float*)ws;                  // BNL f32 = 68.8 MB
  unsigned char* ws_mask = (unsigned char*)(ws + BNL * 4); // BNL u8 = 17.2 MB
  float*         ws_mm   = (float*)(ws + BNL * 5);      // 2048 f32
  float*         ws_mi   = ws_mm + BATCH * NGT;         // 2048 f32

  float* out        = (float*)d_out;
  float* out_labels = out;
  float* out_bboxes = out + (size_t)BATCH * LANCH;
  float* out_scores = out + (size_t)BATCH * LANCH * 5;
  float* out_fg     = out + (size_t)BATCH * LANCH * 5 + (size_t)BATCH * LANCH * NCLS;

  // dense zero for one-hot scores (sparse kernel only writes positives)
  hipMemsetAsync(out_scores, 0, (size_t)BATCH * LANCH * NCLS * sizeof(float), stream);

  dim3 grid(NCHUNK, BATCH);
  k_pairs<<<grid, 256, 0, stream>>>(pred_scores, pred_bboxes, centers,
      gt_labels, gt_bboxes, pad_mask, ws_met, ws_mask, ws_mm, ws_mi);

  k_topk<<<BATCH * NGT, 256, 0, stream>>>(ws_met, ws_mask, pad_mask);

  k_assign<<<grid, 256, 0, stream>>>(pred_scores, pred_bboxes, centers,
      gt_labels, gt_bboxes, pad_mask, ws_mask, ws_mm, ws_mi,
      out_labels, out_bboxes, out_fg);

  k_scores<<<grid, 256, 0, stream>>>(pred_scores, pred_bboxes, centers,
      gt_labels, gt_bboxes, pad_mask, ws_mask, ws_mm, ws_mi,
      out_labels, out_fg, out_scores);
}